// Round 2
// baseline (594.596 us; speedup 1.0000x reference)
//
#include <hip/hip_runtime.h>
#include <math.h>

#define B 4
#define N 8192
#define K 1024
#define ROWS 8           // k-rows per fused/col0 block (16 -> 8: grid 256 -> 512 blocks)
#define KB (K / ROWS)    // 128 k-chunks
#define TPB 512          // threads per block; each thread owns 16 columns
#define BN (B * N)

// Online lse in float: exp args are always <= 0 (no overflow); __expf(-inf)=0.
__device__ __forceinline__ void lse_step(float v, float& m, float& s) {
  float nm = fmaxf(m, v);
  s = s * __expf(m - nm) + __expf(v - nm);
  m = nm;
}
__device__ __forceinline__ void lse_merge(float m2, float s2, float& m, float& s) {
  float nm = fmaxf(m, m2);
  s = s * __expf(m - nm) + s2 * __expf(m2 - nm);
  m = nm;
}

// Partial col lse of g alone (r=0): part[(kb*B+b)*N + n] = lse over the ROWS rows.
__global__ __launch_bounds__(TPB) void col0_kernel(const float* __restrict__ g,
                                                   float* __restrict__ part) {
  int kb = blockIdx.x, b = blockIdx.y;
  const float* gbase = g + ((size_t)(b * K + kb * ROWS)) * N;
  int t = threadIdx.x;
  float cm[4][4], cs[4][4];
#pragma unroll
  for (int j = 0; j < 4; ++j)
#pragma unroll
    for (int q = 0; q < 4; ++q) { cm[j][q] = -INFINITY; cs[j][q] = 0.f; }
  for (int rI = 0; rI < ROWS; ++rI) {
    const float* gr = gbase + (size_t)rI * N;
#pragma unroll
    for (int j = 0; j < 4; ++j) {
      float4 gv = *(const float4*)(gr + j * 2048 + t * 4);
      lse_step(gv.x, cm[j][0], cs[j][0]);
      lse_step(gv.y, cm[j][1], cs[j][1]);
      lse_step(gv.z, cm[j][2], cs[j][2]);
      lse_step(gv.w, cm[j][3], cs[j][3]);
    }
  }
  float* pp = part + ((size_t)(kb * B + b)) * N;
#pragma unroll
  for (int j = 0; j < 4; ++j) {
    float4 o = make_float4(cm[j][0] + __logf(cs[j][0]), cm[j][1] + __logf(cs[j][1]),
                           cm[j][2] + __logf(cs[j][2]), cm[j][3] + __logf(cs[j][3]));
    *(float4*)(pp + j * 2048 + t * 4) = o;
  }
}

// Fold KB partial lses per column -> d[b*N+n] = -lse_k(...)
// Parallelized: 8 threads per column (16 p's each) + LDS merge. Grid = BN/32 = 1024 blocks.
__global__ __launch_bounds__(256) void combine_kernel(const float* __restrict__ part,
                                                      float* __restrict__ d) {
  int c = threadIdx.x & 31;   // column within block
  int pg = threadIdx.x >> 5;  // p-group 0..7
  int idx = blockIdx.x * 32 + c;  // b*N + n
  float m = -INFINITY, s = 0.f;
  const float* pp = part + (size_t)(pg * (KB / 8)) * BN + idx;
#pragma unroll
  for (int i = 0; i < KB / 8; ++i) lse_step(pp[(size_t)i * BN], m, s);
  __shared__ float2 red[8][32];
  red[pg][c] = make_float2(m, s);
  __syncthreads();
  if (threadIdx.x < 32) {
    float mm = red[0][threadIdx.x].x, ss = red[0][threadIdx.x].y;
#pragma unroll
    for (int w = 1; w < 8; ++w)
      lse_merge(red[w][threadIdx.x].x, red[w][threadIdx.x].y, mm, ss);
    d[blockIdx.x * 32 + threadIdx.x] = -(mm + __logf(ss));
  }
}

// One iteration, one HBM sweep: for the block's ROWS rows compute
// r_new[k] = lse_n(g[k,:] + d), then accumulate the next column partials
// lse over those rows of (g[k,n] - r_new[k]).
__global__ __launch_bounds__(TPB) void fused_kernel(const float* __restrict__ g,
                                                    const float* __restrict__ d,
                                                    float* __restrict__ part) {
  int kb = blockIdx.x, b = blockIdx.y;
  const float* gbase = g + ((size_t)(b * K + kb * ROWS)) * N;
  const float* dp = d + b * N;
  int t = threadIdx.x;
  int lane = t & 63, wv = t >> 6;

  __shared__ float2 wpart[ROWS][TPB / 64];
  __shared__ float rnew[ROWS];

  // d values for this thread's 16 columns are row-invariant: load once.
  float4 dv[4];
#pragma unroll
  for (int j = 0; j < 4; ++j) dv[j] = *(const float4*)(dp + j * 2048 + t * 4);

  // Phase 1: per-row lse of (g + d); 4 independent accumulators for ILP on the
  // serial exp chain, merged before the wave shfl reduce.
  for (int rI = 0; rI < ROWS; ++rI) {
    const float* gr = gbase + (size_t)rI * N;
    float m0 = -INFINITY, s0 = 0.f, m1 = -INFINITY, s1 = 0.f;
    float m2 = -INFINITY, s2 = 0.f, m3 = -INFINITY, s3 = 0.f;
#pragma unroll
    for (int j = 0; j < 4; ++j) {
      float4 gv = *(const float4*)(gr + j * 2048 + t * 4);
      lse_step(gv.x + dv[j].x, m0, s0);
      lse_step(gv.y + dv[j].y, m1, s1);
      lse_step(gv.z + dv[j].z, m2, s2);
      lse_step(gv.w + dv[j].w, m3, s3);
    }
    lse_merge(m1, s1, m0, s0);
    lse_merge(m3, s3, m2, s2);
    lse_merge(m2, s2, m0, s0);
#pragma unroll
    for (int off = 32; off; off >>= 1) {
      float mm = __shfl_down(m0, off, 64);
      float ss = __shfl_down(s0, off, 64);
      lse_merge(mm, ss, m0, s0);
    }
    if (lane == 0) wpart[rI][wv] = make_float2(m0, s0);
  }
  __syncthreads();
  if (t < ROWS) {
    float m = -INFINITY, s = 0.f;
#pragma unroll
    for (int w = 0; w < TPB / 64; ++w) lse_merge(wpart[t][w].x, wpart[t][w].y, m, s);
    rnew[t] = m + __logf(s);
  }
  __syncthreads();

  // Phase 2: column-partial accumulation over the same ROWS rows (g re-read, L2/L3-hot)
  float cm[4][4], cs[4][4];
#pragma unroll
  for (int j = 0; j < 4; ++j)
#pragma unroll
    for (int q = 0; q < 4; ++q) { cm[j][q] = -INFINITY; cs[j][q] = 0.f; }
  for (int rI = 0; rI < ROWS; ++rI) {
    float rk = rnew[rI];
    const float* gr = gbase + (size_t)rI * N;
#pragma unroll
    for (int j = 0; j < 4; ++j) {
      float4 gv = *(const float4*)(gr + j * 2048 + t * 4);
      lse_step(gv.x - rk, cm[j][0], cs[j][0]);
      lse_step(gv.y - rk, cm[j][1], cs[j][1]);
      lse_step(gv.z - rk, cm[j][2], cs[j][2]);
      lse_step(gv.w - rk, cm[j][3], cs[j][3]);
    }
  }
  float* pp = part + ((size_t)(kb * B + b)) * N;
#pragma unroll
  for (int j = 0; j < 4; ++j) {
    float4 o = make_float4(cm[j][0] + __logf(cs[j][0]), cm[j][1] + __logf(cs[j][1]),
                           cm[j][2] + __logf(cs[j][2]), cm[j][3] + __logf(cs[j][3]));
    *(float4*)(pp + j * 2048 + t * 4) = o;
  }
}

// out[row] = 1.0; out[B*K+row] = argmax_n(g[row,:] + d[b,:]) (first-index ties)
__global__ __launch_bounds__(256) void argmax_kernel(const float* __restrict__ g,
                                                     const float* __restrict__ d,
                                                     float* __restrict__ out) {
  int row = blockIdx.x;  // b*K + k
  int b = row >> 10;
  const float* gp = g + (size_t)row * N;
  const float* dp = d + b * N;
  float bv = -INFINITY;
  int bi = 0;
#pragma unroll
  for (int j = 0; j < 8; ++j) {
    int n = j * 1024 + threadIdx.x * 4;
    float4 gv = *(const float4*)(gp + n);
    float4 dv = *(const float4*)(dp + n);
    float v;
    v = gv.x + dv.x; if (v > bv) { bv = v; bi = n + 0; }
    v = gv.y + dv.y; if (v > bv) { bv = v; bi = n + 1; }
    v = gv.z + dv.z; if (v > bv) { bv = v; bi = n + 2; }
    v = gv.w + dv.w; if (v > bv) { bv = v; bi = n + 3; }
  }
  __shared__ float svv[256];
  __shared__ int sii[256];
  svv[threadIdx.x] = bv;
  sii[threadIdx.x] = bi;
  __syncthreads();
  for (int off = 128; off > 0; off >>= 1) {
    if (threadIdx.x < off) {
      float v2 = svv[threadIdx.x + off];
      int i2 = sii[threadIdx.x + off];
      float v1 = svv[threadIdx.x];
      int i1 = sii[threadIdx.x];
      if (v2 > v1 || (v2 == v1 && i2 < i1)) {
        svv[threadIdx.x] = v2;
        sii[threadIdx.x] = i2;
      }
    }
    __syncthreads();
  }
  if (threadIdx.x == 0) {
    out[row] = 1.0f;                   // selected_scores forward value (all-true mask)
    out[B * K + row] = (float)sii[0];  // selected_indices as float
  }
}

extern "C" void kernel_launch(void* const* d_in, const int* in_sizes, int n_in,
                              void* d_out, int out_size, void* d_ws, size_t ws_size,
                              hipStream_t stream) {
  // x, routing_token cancel out of the forward outputs (scores constant along k,
  // removed exactly by the first column logsumexp). Only gumbel matters.
  const float* g = (const float*)d_in[2];
  float* out = (float*)d_out;

  char* ws = (char*)d_ws;
  float* d = (float*)ws;                    // 128 KB: d[b*N+n] = -lse_k(...)
  float* part = (float*)(ws + (1 << 20));   // 16 MB: KB x B x N partial lses

  // d1 = -lse_k(g)
  col0_kernel<<<dim3(KB, B), TPB, 0, stream>>>(g, part);
  combine_kernel<<<BN / 32, 256, 0, stream>>>(part, d);
  // iterations 1..7: r_i = lse_n(g + d_i); d_{i+1} = -lse_k(g - r_i)
  for (int it = 0; it < 7; ++it) {
    fused_kernel<<<dim3(KB, B), TPB, 0, stream>>>(g, d, part);
    combine_kernel<<<BN / 32, 256, 0, stream>>>(part, d);
  }
  // 8th row update shifts each row uniformly -> argmax unaffected; skip it.
  argmax_kernel<<<B * K, 256, 0, stream>>>(g, d, out);
}